// Round 6
// baseline (1100.609 us; speedup 1.0000x reference)
//
#include <hip/hip_runtime.h>

#pragma clang fp contract(off)

#define NBOX 4096
#define MBOX 256
#define NBATCH 32
#define GEPS 1e-7f
#define MT 1024
#define NW 16
#define ROUND_CAP 1024
#define DEADROW 0xFFFFu

typedef unsigned long long u64;
typedef unsigned int u32;
typedef unsigned short u16;

#define LDS_BYTES 104448
// dynamic-LDS offsets (bytes)
#define OFF_PRS    0        // float4[4096]  65536
#define OFF_G      65536    // float4[256]   4096
#define OFF_TOP8   69632    // u64[8][256]   16384  (transposed: entry-major)
#define OFF_CMASK  86016    // u32[8]        32     (live-col bitmask)
#define OFF_GAREA  86048    // f32[256]      1024
#define OFF_ROWCOL 87072    // u16[4096]     8192   (argmax col per row; 0xFFFF = matched)
#define OFF_WL     95264    // u16[16][256]  8192
#define OFF_COLWL  103456   // u16[256]      512
#define OFF_WLCNT  103968   // i32[16]
#define OFF_CNT2   104032   // i32[2]
#define OFF_NMATCH 104040   // i32
#define OFF_REDA   104064   // f32[16]
#define OFF_REDB   104128   // f32[16]
#define OFF_REDC   104192   // f32[16]

__device__ __forceinline__ u64 shflxor_u64(u64 x, int m) {
  u32 lo = (u32)x, hi = (u32)(x >> 32);
  lo = __shfl_xor(lo, m, 64);
  hi = __shfl_xor(hi, m, 64);
  return ((u64)hi << 32) | (u64)lo;
}

// exact IEEE, contract off -> bitwise identical everywhere it's computed
__device__ __forceinline__ u32 iou_bits(float4 a, float areaA, float4 g, float gar) {
  #pragma clang fp contract(off)
  float w = fminf(a.z, g.z) - fmaxf(a.x, g.x);
  float h = fminf(a.w, g.w) - fmaxf(a.y, g.y);
  w = fmaxf(w, 0.0f);
  h = fmaxf(h, 0.0f);
  float inter = w * h;
  float uni = (areaA + gar) - inter;
  float v = inter / uni;  // IoU >= 0: float bits order-preserving
  return __float_as_uint(v);
}

__device__ __forceinline__ float giou_loss(float ax1, float ay1, float ax2, float ay2,
                                           float bx1, float by1, float bx2, float by2) {
  #pragma clang fp contract(off)
  float xi1 = fmaxf(ax1, bx1), yi1 = fmaxf(ay1, by1);
  float xi2 = fminf(ax2, bx2), yi2 = fminf(ay2, by2);
  float inter = fmaxf(xi2 - xi1, 0.0f) * fmaxf(yi2 - yi1, 0.0f);
  float area1 = (ax2 - ax1) * (ay2 - ay1);
  float area2 = (bx2 - bx1) * (by2 - by1);
  float uni = (area1 + area2) - inter;
  float iou = inter / (uni + GEPS);
  float xc1 = fminf(ax1, bx1), yc1 = fminf(ay1, by1);
  float xc2 = fmaxf(ax2, bx2), yc2 = fmaxf(ay2, by2);
  float areac = (xc2 - xc1) * (yc2 - yc1);
  float giou = iou - (areac - uni) / (areac + GEPS);
  return 1.0f - giou;
}

// row key: (iou<<9)|(256-c)   -> max == (val desc, col asc)
// col key: (iou<<13)|(4096-r) -> max == (val desc, row asc)
// u64 max over these keys reproduces jnp.argmax flat-index tie-break exactly.

// __launch_bounds__(1024, 4): exactly one 1024-thread block per CU (forced by
// 102KB LDS anyway) -> VGPR budget 128, keeps per-thread u64 arrays in regs.
// R5 post-mortem: without ",4" the compiler capped at 64 VGPRs and spilled
// (WRITE_SIZE 3.8MB of scratch), 3x slowdown.
__global__ __launch_bounds__(MT, 4) void fused_kernel(
    const float4* __restrict__ pr, const float4* __restrict__ gt,
    float* __restrict__ partial) {
  extern __shared__ char smem[];
  float4* prs   = (float4*)(smem + OFF_PRS);
  float4* g     = (float4*)(smem + OFF_G);
  u64 (*top8T)[MBOX] = (u64(*)[MBOX])(smem + OFF_TOP8);
  u32* cmask    = (u32*)(smem + OFF_CMASK);
  float* garea  = (float*)(smem + OFF_GAREA);
  u16* rowcol   = (u16*)(smem + OFF_ROWCOL);
  u16 (*wl)[256] = (u16(*)[256])(smem + OFF_WL);
  u16* colwl    = (u16*)(smem + OFF_COLWL);
  int* wlcnt    = (int*)(smem + OFF_WLCNT);
  int* colcnt2  = (int*)(smem + OFF_CNT2);
  int* nmatch   = (int*)(smem + OFF_NMATCH);
  float* redA   = (float*)(smem + OFF_REDA);
  float* redB   = (float*)(smem + OFF_REDB);
  float* redC   = (float*)(smem + OFF_REDC);

  const int b = blockIdx.x, tid = threadIdx.x;
  const int lane = tid & 63, wid = tid >> 6;
  const float4* prb = pr + (size_t)b * NBOX;

  // ---- stage gt + state init ----
  if (tid < MBOX) {
    float4 gg = gt[(size_t)b * MBOX + tid];
    g[tid] = gg;
    garea[tid] = (gg.z - gg.x) * (gg.w - gg.y);
  }
  if (tid < 8) cmask[tid] = 0xFFFFFFFFu;
  if (tid == 0) { *nmatch = 0; colcnt2[0] = 0; colcnt2[1] = 0; }
  if (lane == 0) wlcnt[wid] = 0;

  // ---- stage pr into LDS + negative-branch loss ----
  float negdiff = 0.0f, possum = 0.0f, negsub = 0.0f;
  #pragma unroll
  for (int k = 0; k < 4; ++k) {
    int r = tid + k * MT;
    float4 a = prb[r];
    prs[r] = a;
    negdiff += giou_loss(a.x, a.y, a.z, a.w, 0.0f, 0.0f, 0.0f, 0.0f);
  }
  __syncthreads();

  // ---- init row pass: 4 rows/thread, serial 256-col scan (g broadcast) ----
  #pragma unroll
  for (int k = 0; k < 4; ++k) {
    int r = tid + k * MT;
    float4 a = prs[r];
    float areaA = (a.z - a.x) * (a.w - a.y);
    u64 best = 0ull;
    for (int c = 0; c < MBOX; ++c) {
      u64 p = ((u64)iou_bits(a, areaA, g[c], garea[c]) << 9) | (u64)(MBOX - c);
      if (p > best) best = p;
    }
    rowcol[r] = (u16)(MBOX - (int)(best & 0x1FFull));
  }
  // ---- init col pass: wave handles 16 cols; per-lane top-8 over 64 rows ----
  for (int cc = 0; cc < 16; ++cc) {
    int j = wid * 16 + cc;
    float4 gb = g[j];
    float gar = garea[j];
    u64 t[8] = {0, 0, 0, 0, 0, 0, 0, 0};
    for (int k = 0; k < 64; ++k) {
      int rr = (k << 6) + lane;
      float4 a = prs[rr];
      float areaA = (a.z - a.x) * (a.w - a.y);
      u64 key = ((u64)iou_bits(a, areaA, gb, gar) << 13) | (u64)(NBOX - rr);
      if (key > t[7]) {
        t[7] = key;
        #pragma unroll
        for (int q = 7; q > 0; --q)
          if (t[q] > t[q - 1]) { u64 tmp = t[q]; t[q] = t[q - 1]; t[q - 1] = tmp; }
      }
    }
    int h = 0;
    for (int e = 0; e < 8; ++e) {
      u64 cand = 0;
      #pragma unroll
      for (int q = 0; q < 8; ++q) if (q == h) cand = t[q];  // static reg index
      u64 m = cand;
      #pragma unroll
      for (int o = 32; o; o >>= 1) {
        u64 q2 = shflxor_u64(m, o);
        if (q2 > m) m = q2;
      }
      if (cand == m && m) h++;  // keys distinct -> unique winner
      if (lane == 0) top8T[e][j] = m;
    }
  }
  __syncthreads();

  // ---- mutual-best rounds (2 barriers/round; R4-proven ordering) ----
  int colmatched = (tid < MBOX) ? 0 : 1;
  for (int round = 0; round < ROUND_CAP; ++round) {
    // P1: owner thread per col: first-live top8 entry + mutual test
    if (!colmatched) {
      const int j = tid;
      u64 ev[8];
      #pragma unroll
      for (int q = 0; q < 8; ++q) ev[q] = top8T[q][j];
      int rw[8]; u32 rcv[8];
      #pragma unroll
      for (int q = 0; q < 8; ++q) {
        rw[q] = NBOX - (int)(ev[q] & 0x1FFFull);
        rcv[q] = rowcol[rw[q]];
      }
      int rsel = -1; u32 rcsel = DEADROW;
      #pragma unroll
      for (int q = 7; q >= 0; --q)
        if (rcv[q] != DEADROW) { rsel = rw[q]; rcsel = rcv[q]; }  // first live
      if (rsel < 0) {
        int x = atomicAdd(&colcnt2[round & 1], 1);  // exhausted -> rebuild this round
        colwl[x] = (u16)j;
      } else if ((int)rcsel == j) {  // mutual best -> greedy-safe match
        colmatched = 1;
        rowcol[rsel] = DEADROW;
        atomicAnd(&cmask[j >> 5], ~(1u << (j & 31)));
        float4 a = prs[rsel];
        float4 gg = g[j];
        possum += giou_loss(a.x, a.y, a.z, a.w, gg.x, gg.y, gg.z, gg.w);
        negsub += giou_loss(a.x, a.y, a.z, a.w, 0.0f, 0.0f, 0.0f, 0.0f);
        atomicAdd(nmatch, 1);
      }
    }
    __syncthreads();  // B1: publish matches/cmask; nmatch stable below
    if (*nmatch >= MBOX) break;
    if (tid == 0) colcnt2[(round + 1) & 1] = 0;

    // P2: detect rows whose argmax col died (4 rows/thread, owner-wave worklist)
    #pragma unroll
    for (int k = 0; k < 4; ++k) {
      int r = tid + k * MT;
      u32 rc = rowcol[r];
      if (rc != DEADROW) {
        if (!((cmask[rc >> 5] >> (rc & 31)) & 1u)) {
          int x = atomicAdd(&wlcnt[wid], 1);
          wl[wid][x] = (u16)r;
        }
      }
    }
    // P3a: wave recomputes its rows, 4 at a time (16 lanes x 16 cols)
    int rcnt = wlcnt[wid];
    for (int base = 0; base < rcnt; base += 4) {
      int idx = base + (lane >> 4);
      bool act = idx < rcnt;
      int rr = (int)wl[wid][act ? idx : 0];
      float4 a = prs[rr];
      float areaA = (a.z - a.x) * (a.w - a.y);
      int cl = lane & 15;
      u64 best = 0ull;
      #pragma unroll
      for (int t2 = 0; t2 < 16; ++t2) {
        int c = cl + (t2 << 4);
        if ((cmask[t2 >> 1] >> (c & 31)) & 1u) {  // c>>5 == t2>>1 (static)
          u64 p = ((u64)iou_bits(a, areaA, g[c], garea[c]) << 9) | (u64)(MBOX - c);
          if (p > best) best = p;
        }
      }
      #pragma unroll
      for (int o = 8; o; o >>= 1) {
        u64 q2 = shflxor_u64(best, o);
        if (q2 > best) best = q2;
      }
      if (act && cl == 0) rowcol[rr] = (u16)(MBOX - (int)(best & 0x1FFull));
    }
    if (lane == 0) wlcnt[wid] = 0;  // after all lanes consumed rcnt (wave-ordered)

    // P3b: rare top-8 rebuilds (wave per col; liveness = rowcol != DEAD)
    int ccnt = colcnt2[round & 1];
    for (int x = wid; x < ccnt; x += NW) {
      int j = (int)colwl[x];
      float4 gb = g[j];
      float gar = garea[j];
      u64 t[8] = {0, 0, 0, 0, 0, 0, 0, 0};
      for (int k = 0; k < 64; ++k) {
        int rr = (k << 6) + lane;
        if (rowcol[rr] != DEADROW) {
          float4 a = prs[rr];
          float areaA = (a.z - a.x) * (a.w - a.y);
          u64 key = ((u64)iou_bits(a, areaA, gb, gar) << 13) | (u64)(NBOX - rr);
          if (key > t[7]) {
            t[7] = key;
            #pragma unroll
            for (int q = 7; q > 0; --q)
              if (t[q] > t[q - 1]) { u64 tmp = t[q]; t[q] = t[q - 1]; t[q - 1] = tmp; }
          }
        }
      }
      int h = 0;
      for (int e = 0; e < 8; ++e) {
        u64 cand = 0;
        #pragma unroll
        for (int q = 0; q < 8; ++q) if (q == h) cand = t[q];
        u64 m = cand;
        #pragma unroll
        for (int o = 32; o; o >>= 1) {
          u64 q2 = shflxor_u64(m, o);
          if (q2 > m) m = q2;
        }
        if (cand == m && m) h++;
        if (lane == 0) top8T[e][j] = m;
      }
    }
    __syncthreads();  // B2
  }

  // ---- final reduce: possum/256 + (negdiff - negsub)/3840 ----
  #pragma unroll
  for (int o = 32; o; o >>= 1) {
    possum  += __shfl_xor(possum, o, 64);
    negsub  += __shfl_xor(negsub, o, 64);
    negdiff += __shfl_xor(negdiff, o, 64);
  }
  if (lane == 0) { redA[wid] = possum; redB[wid] = negsub; redC[wid] = negdiff; }
  __syncthreads();
  if (tid == 0) {
    float pa = 0.0f, ns = 0.0f, ng = 0.0f;
    for (int w = 0; w < NW; ++w) { pa += redA[w]; ns += redB[w]; ng += redC[w]; }
    partial[b] = pa / 256.0f + (ng - ns) / 3840.0f;
  }
}

__global__ void finalize_kernel(const float* __restrict__ partial, float* __restrict__ out) {
  if (threadIdx.x == 0) {
    float s = 0.0f;
    for (int i = 0; i < NBATCH; ++i) s += partial[i];
    out[0] = s / 64.0f;  // /count(=32)/2
  }
}

extern "C" void kernel_launch(void* const* d_in, const int* in_sizes, int n_in,
                              void* d_out, int out_size, void* d_ws, size_t ws_size,
                              hipStream_t stream) {
  (void)in_sizes; (void)n_in; (void)out_size; (void)ws_size;
  const float4* pr = (const float4*)d_in[0];
  const float4* gt = (const float4*)d_in[1];
  float* partial = (float*)d_ws;
  float* out = (float*)d_out;

  // allow >64KB dynamic LDS (idempotent host-side attribute; not a stream op)
  hipFuncSetAttribute((const void*)fused_kernel,
                      hipFuncAttributeMaxDynamicSharedMemorySize, LDS_BYTES);

  hipLaunchKernelGGL(fused_kernel, dim3(NBATCH), dim3(MT), LDS_BYTES, stream,
                     pr, gt, partial);
  hipLaunchKernelGGL(finalize_kernel, dim3(1), dim3(64), 0, stream, partial, out);
}

// Round 7
// 319.345 us; speedup vs baseline: 3.4465x; 3.4465x over previous
//
#include <hip/hip_runtime.h>

#pragma clang fp contract(off)

#define NBOX 4096
#define MBOX 256
#define NBATCH 32
#define GEPS 1e-7f
#define GT 512          // greedy kernel threads (8 waves)
#define GW 8

typedef unsigned long long u64;
typedef unsigned int u32;
typedef unsigned short u16;

// ---- greedy kernel dynamic-LDS layout (bytes) ----
#define OFF_PRS     0        // float4[4096] 65536
#define OFF_TOP8    65536    // u64[8][256]  16384 (entry-major)
#define OFF_CB      81920    // u64[256]     2048  (colbest: global key; 0 = matched/empty)
#define OFF_WM      83968    // u64[8]       64    (wave maxima; only 0..3 used)
#define OFF_G       84032    // float4[256]  4096
#define OFF_GAREA   88128    // f32[256]     1024
#define OFF_ROWLIVE 89152    // u32[128]     512
#define OFF_POS     89664    // u16[256]     512   (next list index to examine)
#define OFF_COLWL   90176    // u16[256]     512
#define OFF_COLCNT  90688    // i32
#define OFF_REDA    90704    // f32[8]
#define OFF_REDB    90736    // f32[8]
#define OFF_REDC    90768    // f32[8]
#define LDS_BYTES   90816

__device__ __forceinline__ u64 shflxor_u64(u64 x, int m) {
  u32 lo = (u32)x, hi = (u32)(x >> 32);
  lo = __shfl_xor(lo, m, 64);
  hi = __shfl_xor(hi, m, 64);
  return ((u64)hi << 32) | (u64)lo;
}

// exact IEEE, contract off -> bitwise identical everywhere it's computed
__device__ __forceinline__ u32 iou_bits(float4 a, float areaA, float4 g, float gar) {
  #pragma clang fp contract(off)
  float w = fminf(a.z, g.z) - fmaxf(a.x, g.x);
  float h = fminf(a.w, g.w) - fmaxf(a.y, g.y);
  w = fmaxf(w, 0.0f);
  h = fmaxf(h, 0.0f);
  float inter = w * h;
  float uni = (areaA + gar) - inter;
  float v = inter / uni;  // IoU >= 0: float bits order-preserving
  return __float_as_uint(v);
}

__device__ __forceinline__ float giou_loss(float ax1, float ay1, float ax2, float ay2,
                                           float bx1, float by1, float bx2, float by2) {
  #pragma clang fp contract(off)
  float xi1 = fmaxf(ax1, bx1), yi1 = fmaxf(ay1, by1);
  float xi2 = fminf(ax2, bx2), yi2 = fminf(ay2, by2);
  float inter = fmaxf(xi2 - xi1, 0.0f) * fmaxf(yi2 - yi1, 0.0f);
  float area1 = (ax2 - ax1) * (ay2 - ay1);
  float area2 = (bx2 - bx1) * (by2 - by1);
  float uni = (area1 + area2) - inter;
  float iou = inter / (uni + GEPS);
  float xc1 = fminf(ax1, bx1), yc1 = fminf(ay1, by1);
  float xc2 = fmaxf(ax2, bx2), yc2 = fmaxf(ay2, by2);
  float areac = (xc2 - xc1) * (yc2 - yc1);
  float giou = iou - (areac - uni) / (areac + GEPS);
  return 1.0f - giou;
}

// col-entry key: (iou<<13)|(4096-r)        -> max == (val desc, row asc)
// global key:    (iou<<22)|((4096-r)<<9)|(256-j) -> max == (val desc, row asc, col asc)
// u64 max over global keys == jnp.argmax flat-index tie-break, exactly.

// one wave per col: lane-local top-8 over 64 rows, then 8x wave-max extraction (R4-proven)
__global__ __launch_bounds__(256) void init_cols(
    const float4* __restrict__ pr, const float4* __restrict__ gt,
    u64* __restrict__ top8G) {
  const int blk = blockIdx.x;
  const int b = blk >> 6, cg = blk & 63;
  const int tid = threadIdx.x, lane = tid & 63, wid = tid >> 6;
  const int j = cg * 4 + wid;
  const float4* prb = pr + (size_t)b * NBOX;
  float4 gb = gt[(size_t)b * MBOX + j];
  float gar = (gb.z - gb.x) * (gb.w - gb.y);
  u64 t[8] = {0, 0, 0, 0, 0, 0, 0, 0};
  for (int k = 0; k < 64; ++k) {
    int r = (k << 6) + lane;  // coalesced
    float4 a = prb[r];
    float areaA = (a.z - a.x) * (a.w - a.y);
    u64 key = ((u64)iou_bits(a, areaA, gb, gar) << 13) | (u64)(NBOX - r);
    if (key > t[7]) {
      t[7] = key;
      #pragma unroll
      for (int q = 7; q > 0; --q)
        if (t[q] > t[q - 1]) { u64 tmp = t[q]; t[q] = t[q - 1]; t[q - 1] = tmp; }
    }
  }
  u64* out = top8G + ((size_t)b * MBOX + j) * 8;
  int h = 0;
  for (int e = 0; e < 8; ++e) {
    u64 cand = 0;
    #pragma unroll
    for (int q = 0; q < 8; ++q) if (q == h) cand = t[q];  // static reg index
    u64 m = cand;
    #pragma unroll
    for (int o = 32; o; o >>= 1) {
      u64 q2 = shflxor_u64(m, o);
      if (q2 > m) m = q2;
    }
    if (cand == m && m) h++;  // keys distinct -> unique winner
    if (lane == 0) out[e] = m;
  }
}

// Exact sequential greedy: 256 steps; per-step argmax over 256 cached col-bests.
__global__ __launch_bounds__(GT) __attribute__((amdgpu_waves_per_eu(1, 8)))
void greedy_kernel(const float4* __restrict__ pr, const float4* __restrict__ gt,
                   const u64* __restrict__ top8G, float* __restrict__ partial) {
  extern __shared__ char smem[];
  float4* prs   = (float4*)(smem + OFF_PRS);
  float4* g     = (float4*)(smem + OFF_G);
  u64* top8T    = (u64*)(smem + OFF_TOP8);     // [e*256 + j]
  u64* colbest  = (u64*)(smem + OFF_CB);
  u64* wavemax  = (u64*)(smem + OFF_WM);
  float* garea  = (float*)(smem + OFF_GAREA);
  u32* rowlive  = (u32*)(smem + OFF_ROWLIVE);
  u16* pos      = (u16*)(smem + OFF_POS);
  u16* colwl    = (u16*)(smem + OFF_COLWL);
  int* colcnt   = (int*)(smem + OFF_COLCNT);
  float* redA   = (float*)(smem + OFF_REDA);
  float* redB   = (float*)(smem + OFF_REDB);
  float* redC   = (float*)(smem + OFF_REDC);

  const int b = blockIdx.x, tid = threadIdx.x;
  const int lane = tid & 63, wid = tid >> 6;
  const float4* prb = pr + (size_t)b * NBOX;

  // ---- stage pr + negative-branch loss ----
  float negdiff = 0.0f, possum = 0.0f, negsub = 0.0f;
  #pragma unroll
  for (int k = 0; k < 8; ++k) {
    int r = tid + k * GT;
    float4 a = prb[r];
    prs[r] = a;
    negdiff += giou_loss(a.x, a.y, a.z, a.w, 0.0f, 0.0f, 0.0f, 0.0f);
  }
  // ---- stage gt / top8 / state ----
  if (tid < MBOX) {
    float4 gg = gt[(size_t)b * MBOX + tid];
    g[tid] = gg;
    garea[tid] = (gg.z - gg.x) * (gg.w - gg.y);
  }
  #pragma unroll
  for (int k = 0; k < 4; ++k) {
    int idx = tid + k * GT;               // coalesced global read
    u64 e = top8G[(size_t)b * (MBOX * 8) + idx];
    top8T[(idx & 7) * MBOX + (idx >> 3)] = e;
  }
  if (tid < 128) rowlive[tid] = 0xFFFFFFFFu;
  if (tid == 0) *colcnt = 0;
  __syncthreads();
  if (tid < MBOX) {
    u64 e0 = top8T[tid];                  // entry 0, all rows live
    colbest[tid] = ((e0 >> 13) << 22) | ((e0 & 0x1FFFull) << 9) | (u64)(MBOX - tid);
    pos[tid] = 1;
  }
  __syncthreads();

  // ---- 256 greedy steps ----
  for (int step = 0; step < MBOX; ++step) {
    // phase A: argmax over colbest (owner waves 0..3)
    u64 cb = 0;
    if (wid < 4) {
      cb = colbest[tid];
      u64 m = cb;
      #pragma unroll
      for (int o = 32; o; o >>= 1) {
        u64 q = shflxor_u64(m, o);
        if (q > m) m = q;
      }
      if (lane == 0) wavemax[wid] = m;
    }
    __syncthreads();  // B1
    if (wid < 4) {
      u64 sel = wavemax[0];
      u64 w1 = wavemax[1], w2 = wavemax[2], w3 = wavemax[3];
      if (w1 > sel) sel = w1;
      if (w2 > sel) sel = w2;
      if (w3 > sel) sel = w3;
      const int i = NBOX - (int)((sel >> 9) & 0x1FFFull);
      const int j = MBOX - (int)(sel & 0x1FFull);
      if (tid == j) {
        // match (i, j): exactly the sequential-greedy selection
        colbest[j] = 0ull;
        rowlive[i >> 5] &= ~(1u << (i & 31));  // single writer this step
        float4 a = prs[i];
        float4 gg = g[j];
        possum += giou_loss(a.x, a.y, a.z, a.w, gg.x, gg.y, gg.z, gg.w);
        negsub += giou_loss(a.x, a.y, a.z, a.w, 0.0f, 0.0f, 0.0f, 0.0f);
      } else if (cb != 0ull && (NBOX - (int)((cb >> 9) & 0x1FFFull)) == i) {
        // my best row just died: advance past dead rows in my sorted list
        int p = pos[tid];
        u64 ne = 0ull;
        while (p < 8) {
          u64 e = top8T[p * MBOX + tid];
          int r = NBOX - (int)(e & 0x1FFFull);
          ++p;
          if (r != i && ((rowlive[r >> 5] >> (r & 31)) & 1u)) { ne = e; break; }
        }
        pos[tid] = (u16)p;
        if (ne) {
          colbest[tid] = ((ne >> 13) << 22) | ((ne & 0x1FFFull) << 9) | (u64)(MBOX - tid);
        } else {
          colbest[tid] = 0ull;  // exhausted: rebuilt below, before next argmax
          int x = atomicAdd(colcnt, 1);
          colwl[x] = (u16)tid;
        }
      }
    }
    if (step == MBOX - 1) break;  // uniform
    __syncthreads();  // B2: publish colbest/rowlive/colwl
    int ccnt = *colcnt;  // uniform (all adds pre-B2)
    if (ccnt) {
      // rebuild exhausted cols: one wave per col, scan live rows
      for (int x = wid; x < ccnt; x += GW) {
        int jj = (int)colwl[x];
        float4 gb = g[jj];
        float gar = garea[jj];
        u64 t[8] = {0, 0, 0, 0, 0, 0, 0, 0};
        for (int k = 0; k < 64; ++k) {
          int rr = (k << 6) + lane;
          if ((rowlive[rr >> 5] >> (rr & 31)) & 1u) {
            float4 a = prs[rr];
            float areaA = (a.z - a.x) * (a.w - a.y);
            u64 key = ((u64)iou_bits(a, areaA, gb, gar) << 13) | (u64)(NBOX - rr);
            if (key > t[7]) {
              t[7] = key;
              #pragma unroll
              for (int q = 7; q > 0; --q)
                if (t[q] > t[q - 1]) { u64 tmp = t[q]; t[q] = t[q - 1]; t[q - 1] = tmp; }
            }
          }
        }
        int h = 0;
        for (int e = 0; e < 8; ++e) {
          u64 cand = 0;
          #pragma unroll
          for (int q = 0; q < 8; ++q) if (q == h) cand = t[q];
          u64 m = cand;
          #pragma unroll
          for (int o = 32; o; o >>= 1) {
            u64 q2 = shflxor_u64(m, o);
            if (q2 > m) m = q2;
          }
          if (cand == m && m) h++;
          if (lane == 0) {
            top8T[e * MBOX + jj] = m;
            if (e == 0) {  // >=3840 live rows -> m nonzero, live
              colbest[jj] = ((m >> 13) << 22) | ((m & 0x1FFFull) << 9) | (u64)(MBOX - jj);
              pos[jj] = 1;
            }
          }
        }
      }
      if (tid == 0) *colcnt = 0;
      __syncthreads();  // B3 (rare)
    }
  }

  // ---- final reduce: possum/256 + (negdiff - negsub)/3840 ----
  #pragma unroll
  for (int o = 32; o; o >>= 1) {
    possum  += __shfl_xor(possum, o, 64);
    negsub  += __shfl_xor(negsub, o, 64);
    negdiff += __shfl_xor(negdiff, o, 64);
  }
  if (lane == 0) { redA[wid] = possum; redB[wid] = negsub; redC[wid] = negdiff; }
  __syncthreads();
  if (tid == 0) {
    float pa = 0.0f, ns = 0.0f, ng = 0.0f;
    for (int w = 0; w < GW; ++w) { pa += redA[w]; ns += redB[w]; ng += redC[w]; }
    partial[b] = pa / 256.0f + (ng - ns) / 3840.0f;
  }
}

__global__ void finalize_kernel(const float* __restrict__ partial, float* __restrict__ out) {
  if (threadIdx.x == 0) {
    float s = 0.0f;
    for (int i = 0; i < NBATCH; ++i) s += partial[i];
    out[0] = s / 64.0f;  // /count(=32)/2
  }
}

extern "C" void kernel_launch(void* const* d_in, const int* in_sizes, int n_in,
                              void* d_out, int out_size, void* d_ws, size_t ws_size,
                              hipStream_t stream) {
  (void)in_sizes; (void)n_in; (void)out_size; (void)ws_size;
  const float4* pr = (const float4*)d_in[0];
  const float4* gt = (const float4*)d_in[1];
  char* ws = (char*)d_ws;
  u64* top8G = (u64*)ws;                              // 512 KB
  float* partial = (float*)(ws + NBATCH * MBOX * 8 * 8);
  float* out = (float*)d_out;

  // allow >64KB dynamic LDS (idempotent host-side attribute; not a stream op)
  hipFuncSetAttribute((const void*)greedy_kernel,
                      hipFuncAttributeMaxDynamicSharedMemorySize, LDS_BYTES);

  hipLaunchKernelGGL(init_cols, dim3(NBATCH * 64), dim3(256), 0, stream, pr, gt, top8G);
  hipLaunchKernelGGL(greedy_kernel, dim3(NBATCH), dim3(GT), LDS_BYTES, stream,
                     pr, gt, top8G, partial);
  hipLaunchKernelGGL(finalize_kernel, dim3(1), dim3(64), 0, stream, partial, out);
}